// Round 1
// baseline (887.468 us; speedup 1.0000x reference)
//
#include <hip/hip_runtime.h>
#include <hip/hip_bf16.h>

// MoE: N=8192 tokens, D=1024, H=4096, E=8 experts, top-k=2.
// Sparse grouped-GEMM implementation (only top-2 experts per token computed).

#define NTOK 8192
#define DDIM 1024
#define HDIM 4096
#define NEXP 8
#define NASSIGN (NTOK * 2)   // 16384 (token, expert) assignments
#define MAX_MTILES 136       // max ceil-sum of per-expert 128-row tiles is 135

typedef __bf16 bf16_t;
typedef __bf16 bf16x8 __attribute__((ext_vector_type(8)));
typedef float f32x4 __attribute__((ext_vector_type(4)));

// async global->LDS, 16B per lane; LDS dest = wave-uniform base + lane*16
#define GLOAD16(gptr, lptr)                                                    \
  __builtin_amdgcn_global_load_lds(                                            \
      (const __attribute__((address_space(1))) void*)(gptr),                   \
      (__attribute__((address_space(3))) void*)(lptr), 16, 0, 0)

// ---------------- conversion kernels ----------------

__global__ void __launch_bounds__(256) cvt_x_kernel(
    const float* __restrict__ in, bf16_t* __restrict__ out) {
  const int i = (blockIdx.x * 256 + threadIdx.x) * 8;
  const float4 a = *(const float4*)(in + i);
  const float4 b = *(const float4*)(in + i + 4);
  bf16x8 o;
  o[0] = (bf16_t)a.x; o[1] = (bf16_t)a.y; o[2] = (bf16_t)a.z; o[3] = (bf16_t)a.w;
  o[4] = (bf16_t)b.x; o[5] = (bf16_t)b.y; o[6] = (bf16_t)b.z; o[7] = (bf16_t)b.w;
  *(bf16x8*)(out + i) = o;
}

// in: [E][R][C] f32  ->  out: [E][C][R] bf16   (tiled 32x32 transpose)
__global__ void __launch_bounds__(256) transpose_cvt_kernel(
    const float* __restrict__ in, bf16_t* __restrict__ out, int R, int C) {
  __shared__ float tile[32][33];
  const size_t mat = (size_t)R * C;
  const float* ip = in + (size_t)blockIdx.z * mat;
  bf16_t* op = out + (size_t)blockIdx.z * mat;
  const int c0 = blockIdx.x * 32, r0 = blockIdx.y * 32;
  const int tx = threadIdx.x, ty = threadIdx.y;  // (32, 8)
#pragma unroll
  for (int i = 0; i < 4; ++i) {
    const int r = ty + 8 * i;
    tile[r][tx] = ip[(size_t)(r0 + r) * C + (c0 + tx)];
  }
  __syncthreads();
#pragma unroll
  for (int i = 0; i < 4; ++i) {
    const int r = ty + 8 * i;
    op[(size_t)(c0 + r) * R + (r0 + tx)] = (bf16_t)tile[tx][r];
  }
}

// ---------------- router ----------------

__global__ void __launch_bounds__(256) router_kernel(
    const float* __restrict__ x, const float* __restrict__ Wr,
    const float* __restrict__ br, int2* __restrict__ ids,
    float2* __restrict__ prs, int* __restrict__ counts) {
  const int n = blockIdx.x;
  const int t = threadIdx.x;
  const float* xr = x + (size_t)n * DDIM;
  float acc[NEXP];
#pragma unroll
  for (int e = 0; e < NEXP; ++e) acc[e] = 0.f;
#pragma unroll
  for (int j = 0; j < DDIM / 256; ++j) {
    const int d = t + 256 * j;
    const float xv = xr[d];
    const float* w = Wr + (size_t)d * NEXP;
#pragma unroll
    for (int e = 0; e < NEXP; ++e) acc[e] += xv * w[e];
  }
  __shared__ float red[256][NEXP];
#pragma unroll
  for (int e = 0; e < NEXP; ++e) red[t][e] = acc[e];
  __syncthreads();
  for (int s = 128; s >= 1; s >>= 1) {  // fixed tree -> deterministic logits
    if (t < s) {
#pragma unroll
      for (int e = 0; e < NEXP; ++e) red[t][e] += red[t + s][e];
    }
    __syncthreads();
  }
  if (t == 0) {
    float l[NEXP];
#pragma unroll
    for (int e = 0; e < NEXP; ++e) l[e] = red[0][e] + br[e];
    // top-2 on logits (softmax is monotone); strict > = lowest-index tie-break
    int i1 = 0; float v1 = l[0];
    for (int e = 1; e < NEXP; ++e)
      if (l[e] > v1) { v1 = l[e]; i1 = e; }
    int i2 = (i1 == 0) ? 1 : 0; float v2 = l[i2];
    for (int e = 0; e < NEXP; ++e)
      if (e != i1 && l[e] > v2) { v2 = l[e]; i2 = e; }
    // stable softmax probs for the two selected experts
    float denom = 0.f;
    for (int e = 0; e < NEXP; ++e) denom += expf(l[e] - v1);
    const float p1 = expf(v1 - v1) / denom;
    const float p2 = expf(v2 - v1) / denom;
    ids[n] = make_int2(i1, i2);
    prs[n] = make_float2(p1, p2);
    atomicAdd(&counts[i1], 1);
    atomicAdd(&counts[i2], 1);
  }
}

// offsets + tile map (device-side, counts known only on device)
__global__ void scan_kernel(const int* __restrict__ counts,
                            int* __restrict__ offsets, int* __restrict__ tmap) {
  if (threadIdx.x != 0 || blockIdx.x != 0) return;
  int off = 0, nt = 0;
  for (int e = 0; e < NEXP; ++e) {
    offsets[e] = off;
    const int c = counts[e];
    for (int m0 = 0; m0 < c; m0 += 128) {
      tmap[nt] = e;
      tmap[MAX_MTILES + nt] = m0;
      ++nt;
    }
    off += c;
  }
  offsets[NEXP] = off;
  tmap[2 * MAX_MTILES] = nt;
}

__global__ void __launch_bounds__(256) scatter_kernel(
    const int2* __restrict__ ids, const float2* __restrict__ prs,
    const int* __restrict__ offsets, int* __restrict__ cursor,
    int* __restrict__ btok, float* __restrict__ bprob) {
  const int n = blockIdx.x * 256 + threadIdx.x;
  if (n >= NTOK) return;
  const int2 id = ids[n];
  const float2 pr = prs[n];
  int p = atomicAdd(&cursor[id.x], 1);
  btok[offsets[id.x] + p] = n;
  bprob[offsets[id.x] + p] = pr.x;
  p = atomicAdd(&cursor[id.y], 1);
  btok[offsets[id.y] + p] = n;
  bprob[offsets[id.y] + p] = pr.y;
}

// importance + aux loss (single block, deterministic tree)
__global__ void __launch_bounds__(256) aux_kernel(
    const int2* __restrict__ ids, const float2* __restrict__ prs,
    float* __restrict__ aux_out) {
  const int t = threadIdx.x;
  float imp[NEXP];
#pragma unroll
  for (int e = 0; e < NEXP; ++e) imp[e] = 0.f;
  for (int n = t; n < NTOK; n += 256) {
    const int2 id = ids[n];
    const float2 pr = prs[n];
#pragma unroll
    for (int e = 0; e < NEXP; ++e)
      imp[e] += (id.x == e ? pr.x : 0.f) + (id.y == e ? pr.y : 0.f);
  }
  __shared__ float red[256][NEXP];
#pragma unroll
  for (int e = 0; e < NEXP; ++e) red[t][e] = imp[e];
  __syncthreads();
  for (int s = 128; s >= 1; s >>= 1) {
    if (t < s) {
#pragma unroll
      for (int e = 0; e < NEXP; ++e) red[t][e] += red[t + s][e];
    }
    __syncthreads();
  }
  if (t == 0) {
    float m = 0.f;
    for (int e = 0; e < NEXP; ++e) m += red[0][e];
    m *= (1.f / NEXP);
    float v = 0.f;
    for (int e = 0; e < NEXP; ++e) {
      const float d = red[0][e] - m;
      v += d * d;
    }
    v *= (1.f / (NEXP - 1));  // ddof=1
    aux_out[0] = v / (m * m + 1e-9f);
  }
}

// ---------------- grouped GEMMs (m97 structure: 128x128x32, gload_lds 16B) ----

// h[assign, :] = relu(x[btok[assign]] @ W1[e] + b1[e]),  N-dim = HDIM, K = DDIM
__global__ void __launch_bounds__(256) gemm1_kernel(
    const bf16_t* __restrict__ xb, const bf16_t* __restrict__ W1t,
    const float* __restrict__ b1, const int* __restrict__ btok,
    const int* __restrict__ offsets, const int* __restrict__ counts,
    const int* __restrict__ tmap, bf16_t* __restrict__ h) {
  const int tidx = blockIdx.y;
  if (tidx >= tmap[2 * MAX_MTILES]) return;
  const int e = tmap[tidx];
  const int m0 = tmap[MAX_MTILES + tidx];
  const int cnt = counts[e];
  const int aoff = offsets[e];
  const int n0 = blockIdx.x * 128;

  __shared__ __align__(16) bf16_t Al[128 * 32];
  __shared__ __align__(16) bf16_t Bl[128 * 32];

  const int tid = threadIdx.x;
  const int wave = tid >> 6;
  const int lane = tid & 63;

  // per-thread global source bases for the 2 staging rounds (fixed over K)
  const bf16_t* asrc[2];
  const bf16_t* bsrc[2];
#pragma unroll
  for (int j = 0; j < 2; ++j) {
    const int fi = j * 256 + tid;       // 16B-chunk index in [0,512)
    const int r = fi >> 2;              // tile row
    const int kc = (fi & 3) * 8;        // k element offset
    int arow = m0 + r;
    if (arow > cnt - 1) arow = cnt - 1;  // clamp (stores masked later)
    const int tok = btok[aoff + arow];
    asrc[j] = xb + (size_t)tok * DDIM + kc;
    bsrc[j] = W1t + ((size_t)e * HDIM + n0 + r) * DDIM + kc;
  }
  char* AlB = (char*)Al + wave * 1024;
  char* BlB = (char*)Bl + wave * 1024;

  f32x4 acc[4][4];
#pragma unroll
  for (int mt = 0; mt < 4; ++mt)
#pragma unroll
    for (int nt = 0; nt < 4; ++nt) acc[mt][nt] = (f32x4){0.f, 0.f, 0.f, 0.f};

  const int wr = (wave >> 1) * 64;
  const int wc = (wave & 1) * 64;
  const int lrow = lane & 15;
  const int lk = (lane >> 4) * 8;

  for (int k0 = 0; k0 < DDIM; k0 += 32) {
    GLOAD16(asrc[0] + k0, AlB);
    GLOAD16(asrc[1] + k0, AlB + 4096);
    GLOAD16(bsrc[0] + k0, BlB);
    GLOAD16(bsrc[1] + k0, BlB + 4096);
    __syncthreads();
    bf16x8 af[4], bfr[4];
#pragma unroll
    for (int mt = 0; mt < 4; ++mt)
      af[mt] = *(const bf16x8*)&Al[(wr + mt * 16 + lrow) * 32 + lk];
#pragma unroll
    for (int nt = 0; nt < 4; ++nt)
      bfr[nt] = *(const bf16x8*)&Bl[(wc + nt * 16 + lrow) * 32 + lk];
#pragma unroll
    for (int mt = 0; mt < 4; ++mt)
#pragma unroll
      for (int nt = 0; nt < 4; ++nt)
        acc[mt][nt] = __builtin_amdgcn_mfma_f32_16x16x32_bf16(
            af[mt], bfr[nt], acc[mt][nt], 0, 0, 0);
    __syncthreads();
  }

  // epilogue: h = relu(acc + b1), bf16
  const int rbase = (lane >> 4) * 4;
  const float* b1e = b1 + (size_t)e * HDIM + n0;
#pragma unroll
  for (int nt = 0; nt < 4; ++nt) {
    const int cl = wc + nt * 16 + lrow;
    const float bb = b1e[cl];
#pragma unroll
    for (int mt = 0; mt < 4; ++mt) {
#pragma unroll
      for (int r = 0; r < 4; ++r) {
        const int grow = wr + mt * 16 + rbase + r;
        if (m0 + grow < cnt)
          h[(size_t)(aoff + m0 + grow) * HDIM + (n0 + cl)] =
              (bf16_t)fmaxf(acc[mt][nt][r] + bb, 0.f);
      }
    }
  }
}

// out[tok] += p * (h[assign] @ W2[e] + b2[e]),  N-dim = DDIM, K = HDIM
__global__ void __launch_bounds__(256) gemm2_kernel(
    const bf16_t* __restrict__ h, const bf16_t* __restrict__ W2t,
    const float* __restrict__ b2, const int* __restrict__ btok,
    const float* __restrict__ bprob, const int* __restrict__ offsets,
    const int* __restrict__ counts, const int* __restrict__ tmap,
    float* __restrict__ out) {
  const int tidx = blockIdx.y;
  if (tidx >= tmap[2 * MAX_MTILES]) return;
  const int e = tmap[tidx];
  const int m0 = tmap[MAX_MTILES + tidx];
  const int cnt = counts[e];
  const int aoff = offsets[e];
  const int n0 = blockIdx.x * 128;

  __shared__ __align__(16) bf16_t Al[128 * 32];
  __shared__ __align__(16) bf16_t Bl[128 * 32];

  const int tid = threadIdx.x;
  const int wave = tid >> 6;
  const int lane = tid & 63;

  const bf16_t* asrc[2];
  const bf16_t* bsrc[2];
#pragma unroll
  for (int j = 0; j < 2; ++j) {
    const int fi = j * 256 + tid;
    const int r = fi >> 2;
    const int kc = (fi & 3) * 8;
    int arow = m0 + r;
    if (arow > cnt - 1) arow = cnt - 1;
    asrc[j] = h + (size_t)(aoff + arow) * HDIM + kc;
    bsrc[j] = W2t + ((size_t)e * DDIM + n0 + r) * HDIM + kc;
  }
  char* AlB = (char*)Al + wave * 1024;
  char* BlB = (char*)Bl + wave * 1024;

  f32x4 acc[4][4];
#pragma unroll
  for (int mt = 0; mt < 4; ++mt)
#pragma unroll
    for (int nt = 0; nt < 4; ++nt) acc[mt][nt] = (f32x4){0.f, 0.f, 0.f, 0.f};

  const int wr = (wave >> 1) * 64;
  const int wc = (wave & 1) * 64;
  const int lrow = lane & 15;
  const int lk = (lane >> 4) * 8;

  for (int k0 = 0; k0 < HDIM; k0 += 32) {
    GLOAD16(asrc[0] + k0, AlB);
    GLOAD16(asrc[1] + k0, AlB + 4096);
    GLOAD16(bsrc[0] + k0, BlB);
    GLOAD16(bsrc[1] + k0, BlB + 4096);
    __syncthreads();
    bf16x8 af[4], bfr[4];
#pragma unroll
    for (int mt = 0; mt < 4; ++mt)
      af[mt] = *(const bf16x8*)&Al[(wr + mt * 16 + lrow) * 32 + lk];
#pragma unroll
    for (int nt = 0; nt < 4; ++nt)
      bfr[nt] = *(const bf16x8*)&Bl[(wc + nt * 16 + lrow) * 32 + lk];
#pragma unroll
    for (int mt = 0; mt < 4; ++mt)
#pragma unroll
      for (int nt = 0; nt < 4; ++nt)
        acc[mt][nt] = __builtin_amdgcn_mfma_f32_16x16x32_bf16(
            af[mt], bfr[nt], acc[mt][nt], 0, 0, 0);
    __syncthreads();
  }

  // epilogue: out[tok] += p * (acc + b2)   (2 commutative atomics per element)
  const int rbase = (lane >> 4) * 4;
  const float* b2e = b2 + (size_t)e * DDIM + n0;
  float bb[4];
#pragma unroll
  for (int nt = 0; nt < 4; ++nt) bb[nt] = b2e[wc + nt * 16 + lrow];
#pragma unroll
  for (int mt = 0; mt < 4; ++mt) {
#pragma unroll
    for (int r = 0; r < 4; ++r) {
      const int grow = wr + mt * 16 + rbase + r;
      if (m0 + grow < cnt) {
        const int assign = aoff + m0 + grow;
        const int tok = btok[assign];
        const float p = bprob[assign];
        float* orow = out + (size_t)tok * DDIM + n0;
#pragma unroll
        for (int nt = 0; nt < 4; ++nt) {
          const int cl = wc + nt * 16 + lrow;
          atomicAdd(&orow[cl], (acc[mt][nt][r] + bb[nt]) * p);
        }
      }
    }
  }
}

// ---------------- launch ----------------

extern "C" void kernel_launch(void* const* d_in, const int* in_sizes, int n_in,
                              void* d_out, int out_size, void* d_ws,
                              size_t ws_size, hipStream_t stream) {
  const float* x = (const float*)d_in[0];
  const float* Wr = (const float*)d_in[1];
  const float* br = (const float*)d_in[2];
  const float* W1 = (const float*)d_in[3];
  const float* b1 = (const float*)d_in[4];
  const float* W2 = (const float*)d_in[5];
  const float* b2 = (const float*)d_in[6];
  // d_in[7] = k (fixed 2, hardcoded)

  // workspace layout (~286 MB)
  char* w = (char*)d_ws;
  auto alloc = [&](size_t bytes) -> char* {
    char* p = w;
    w += (bytes + 255) & ~(size_t)255;
    return p;
  };
  bf16_t* xb = (bf16_t*)alloc((size_t)NTOK * DDIM * 2);
  bf16_t* W1t = (bf16_t*)alloc((size_t)NEXP * DDIM * HDIM * 2);
  bf16_t* W2t = (bf16_t*)alloc((size_t)NEXP * DDIM * HDIM * 2);
  bf16_t* hbuf = (bf16_t*)alloc((size_t)NASSIGN * HDIM * 2);
  int* btok = (int*)alloc(NASSIGN * 4);
  float* bprob = (float*)alloc(NASSIGN * 4);
  int2* ids = (int2*)alloc(NTOK * 8);
  float2* prs = (float2*)alloc(NTOK * 8);
  int* ctrl = (int*)alloc(64);     // counts[8] + cursor[8]
  int* offsets = (int*)alloc(64);  // 9 used
  int* tmap = (int*)alloc((2 * MAX_MTILES + 1) * 4);
  int* counts = ctrl;
  int* cursor = ctrl + 8;
  (void)in_sizes; (void)n_in; (void)ws_size;

  float* out = (float*)d_out;

  hipMemsetAsync(d_out, 0, (size_t)out_size * 4, stream);  // atomics target
  hipMemsetAsync(ctrl, 0, 64, stream);

  cvt_x_kernel<<<NTOK * DDIM / 2048, 256, 0, stream>>>(x, xb);
  transpose_cvt_kernel<<<dim3(HDIM / 32, DDIM / 32, NEXP), dim3(32, 8), 0,
                         stream>>>(W1, W1t, DDIM, HDIM);
  transpose_cvt_kernel<<<dim3(DDIM / 32, HDIM / 32, NEXP), dim3(32, 8), 0,
                         stream>>>(W2, W2t, HDIM, DDIM);
  router_kernel<<<NTOK, 256, 0, stream>>>(x, Wr, br, ids, prs, counts);
  scan_kernel<<<1, 1, 0, stream>>>(counts, offsets, tmap);
  scatter_kernel<<<NTOK / 256, 256, 0, stream>>>(ids, prs, offsets, cursor,
                                                 btok, bprob);
  aux_kernel<<<1, 256, 0, stream>>>(ids, prs, out + (size_t)NTOK * DDIM);
  gemm1_kernel<<<dim3(HDIM / 128, MAX_MTILES - 1, 1), 256, 0, stream>>>(
      xb, W1t, b1, btok, offsets, counts, tmap, hbuf);
  gemm2_kernel<<<dim3(DDIM / 128, MAX_MTILES - 1, 1), 256, 0, stream>>>(
      hbuf, W2t, b2, btok, bprob, offsets, counts, tmap, out);
}